// Round 6
// baseline (2673.253 us; speedup 1.0000x reference)
//
#include <hip/hip_runtime.h>
#include <stdint.h>
#include <stddef.h>

// ---------------- problem constants ----------------
#define BATCH 64
#define TT    512
#define DIM   256
#define HID   256
#define MROWS (BATCH*TT)     // 32768

typedef unsigned short u16;
typedef unsigned int u32;
typedef __attribute__((ext_vector_type(8))) short  short8;   // 8 x bf16 bits (4 VGPRs) - MFMA A/B frag
typedef __attribute__((ext_vector_type(4))) float  f32x4;    // MFMA C/D frag
typedef __attribute__((ext_vector_type(4))) int    int4v;
typedef __attribute__((ext_vector_type(4))) unsigned short u16x4;

__device__ __forceinline__ u16 bf16_hi(float f) {
    union { float f; unsigned u; } v; v.f = f;
    unsigned r = v.u + 0x7fffu + ((v.u >> 16) & 1u);   // RNE
    return (u16)(r >> 16);
}
__device__ __forceinline__ float bf16f(u16 b) {
    union { unsigned u; float f; } v; v.u = ((unsigned)b) << 16;
    return v.f;
}
__device__ __forceinline__ float fsigmoid(float x) { return 1.f / (1.f + __expf(-x)); }
__device__ __forceinline__ float ftanh(float x) {
    x = fminf(15.f, fmaxf(-15.f, x));                  // avoid inf/inf
    float e = __expf(2.f * x);
    return (e - 1.f) / (e + 1.f);
}

// ---------------- prep: quantize weights to bf16 hi/lo with GATE-INTERLEAVED row permutation ----------------
// Prepped layout per matrix: [2 dir][16 s][4 w][16 m][K], where m = unit_local*4 + gate.
// This makes the MFMA C-layout deliver all 4 gates of one unit to one thread (cell update in regs).
// elems: Wih0 524288 | Whh0 524288 | Wih1 1048576 | Whh1 524288 = 2,621,440; + bsum 4096 + hx 131072
__global__ __launch_bounds__(256) void k_prep(
    const float* __restrict__ Wih0f, const float* __restrict__ Whh0f, const float* __restrict__ bih0f, const float* __restrict__ bhh0f,
    const float* __restrict__ Wih0b, const float* __restrict__ Whh0b, const float* __restrict__ bih0b, const float* __restrict__ bhh0b,
    const float* __restrict__ Wih1f, const float* __restrict__ Whh1f, const float* __restrict__ bih1f, const float* __restrict__ bhh1f,
    const float* __restrict__ Wih1b, const float* __restrict__ Whh1b, const float* __restrict__ bih1b, const float* __restrict__ bhh1b,
    u16* __restrict__ WihQ0hi, u16* __restrict__ WihQ0lo,
    u16* __restrict__ WhhQ0hi, u16* __restrict__ WhhQ0lo,
    u16* __restrict__ WihQ1hi, u16* __restrict__ WihQ1lo,
    u16* __restrict__ WhhQ1hi, u16* __restrict__ WhhQ1lo,
    float* __restrict__ bsum, u32* __restrict__ hxp)
{
    const int i = blockIdx.x * 256 + threadIdx.x;
    if (i < 2621440) {
        const float* srcf; const float* srcb; u16* dhi; u16* dlo; int off; int K;
        if      (i <  524288) { srcf = Wih0f; srcb = Wih0b; dhi = WihQ0hi; dlo = WihQ0lo; off = i;           K = 256; }
        else if (i < 1048576) { srcf = Whh0f; srcb = Whh0b; dhi = WhhQ0hi; dlo = WhhQ0lo; off = i -  524288; K = 256; }
        else if (i < 2097152) { srcf = Wih1f; srcb = Wih1b; dhi = WihQ1hi; dlo = WihQ1lo; off = i - 1048576; K = 512; }
        else                  { srcf = Whh1f; srcb = Whh1b; dhi = WhhQ1hi; dlo = WhhQ1lo; off = i - 2097152; K = 256; }
        const int SZ = 1024 * K;
        const int dd = off / SZ;
        const int o  = off - dd * SZ;
        const int pr = o / K;
        const int k  = o - pr * K;
        const int s  = pr >> 6;
        const int ww = (pr >> 4) & 3;
        const int m  = pr & 15;
        const int src_row = (m & 3) * 256 + s * 16 + ww * 4 + (m >> 2);   // gate*256 + unit
        const float v = (dd ? srcb : srcf)[src_row * K + k];
        const u16 h = bf16_hi(v);
        dhi[off] = h;
        dlo[off] = bf16_hi(v - bf16f(h));
    } else if (i < 2621440 + 4096) {
        const int j = i - 2621440;
        const float* bihs[4] = { bih0f, bih0b, bih1f, bih1b };
        const float* bhhs[4] = { bhh0f, bhh0b, bhh1f, bhh1b };
        const int ld = j >> 10, k = j & 1023;
        bsum[j] = bihs[ld][k] + bhhs[ld][k];
    } else if (i < 2621440 + 4096 + 131072) {
        // hx: 2 layer-regions x [2 parity][2 dir][64][256] u32, tag = bit16 (LSB of lo16).
        // parity0 first consumed T=2 (expect tag 1) -> init 0; parity1 first consumed T=1 (expect 0) -> init 1.
        const int j = i - (2621440 + 4096);
        hxp[j] = ((j >> 15) & 1) ? 0x00010000u : 0u;
    }
}

// ---------------- embedding gather -> A0 (bf16 hi only) ----------------
__global__ __launch_bounds__(256) void k_gather(
    const int* __restrict__ x, const float* __restrict__ embed, u16* __restrict__ A0)
{
    const int row = blockIdx.x * 4 + (threadIdx.x >> 6);
    const int col = (threadIdx.x & 63) * 4;
    const int xi = x[row];
    const f32x4 v = *(const f32x4*)(embed + (size_t)xi * DIM + col);
    u16x4 h;
    #pragma unroll
    for (int i = 0; i < 4; i++) h[i] = bf16_hi(v[i]);
    *(u16x4*)(A0 + (size_t)row * DIM + col) = h;
}

// ---------------- persistent bidirectional LSTM layer ----------------
// grid = 128 blocks: bid = s*8 + d*4 + c (s=16-unit slice, d=dir, c=batch-chunk of 16).
// ONE-HOP self-validating exchange (tag bit16 = (T>>1)&1, parity double-buffer) as round 5.
// NEW: gate-interleaved W rows -> cell update fully in registers (no g_lds, 2 barriers/step);
//      async x-stage: global loads issued to regs BEFORE the h-poll, LDS-written after.
template<int KIN, bool WRITE_H, bool POOL>
__global__ __launch_bounds__(256, 1) void k_lstm(
    const u16* __restrict__ Xin,                   // layer0: A0 [32768][256]; layer1: H0 [32768][512]
    const u16* __restrict__ WhhHi, const u16* __restrict__ WhhLo,   // [2][16][4][16][256]
    const u16* __restrict__ WihHi, const u16* __restrict__ WihLo,   // [2][16][4][16][KIN]
    const float* __restrict__ bsum,                // [2][1024] for this layer (gate*256+unit)
    const int* __restrict__ slen,
    u16* __restrict__ H0,                          // layer0 out (hi) [32768][512] or null
    float* __restrict__ outp,                      // [64][512] pooled out or null
    u32* __restrict__ hx)                          // [2 parity][2 dir][64][256] packed hi|lo(+tag)
{
    constexpr int KV = KIN / 32;        // MFMA k-blocks for input proj
    constexpr int CR = KIN / 8;         // 16B chunks per x row
    constexpr int NST = (16 * CR) / 256;

    const int bid = blockIdx.x;
    const int s = bid >> 3;
    const int d = (bid >> 2) & 1;
    const int c = bid & 3;
    const int tid = threadIdx.x;
    const int l = tid & 63, w = tid >> 6;

    __shared__ u16 xs[16 * KIN];        // swizzled x-tile (bf16 hi)
    __shared__ u16 hs_hi[16 * 256];
    __shared__ u16 hs_lo[16 * 256];
    __shared__ u32 ho_pack[16 * 17];    // [batch][unit] packed hi|lo(+tag), stride 17 (bank spread)
    __shared__ int lens_sh[16];
    __shared__ int maxlen_sh;

    if (tid < 16) lens_sh[tid] = slen[c * 16 + tid];
    __syncthreads();
    if (tid == 0) {
        int m = 0;
        #pragma unroll
        for (int i = 0; i < 16; i++) m = max(m, lens_sh[i]);
        maxlen_sh = m;
    }
    __syncthreads();
    const int maxlen = maxlen_sh;

    // ---- persistent register-resident weight fragments ----
    // wave w covers units s*16 + w*4 .. +3, rows m = unit_local*4 + gate (permuted in k_prep)
    const int wblk = (d * 16 + s) * 4 + w;
    short8 wfh[8], wfl[8];
    #pragma unroll
    for (int kv = 0; kv < 8; kv++) {
        const size_t off = (size_t)(wblk * 16 + (l & 15)) * 256 + kv * 32 + ((l >> 4) << 3);
        wfh[kv] = *(const short8*)(WhhHi + off);
        wfl[kv] = *(const short8*)(WhhLo + off);
    }
    short8 uih[KV], uil[KV];
    #pragma unroll
    for (int kv = 0; kv < KV; kv++) {
        const size_t off = (size_t)(wblk * 16 + (l & 15)) * KIN + kv * 32 + ((l >> 4) << 3);
        uih[kv] = *(const short8*)(WihHi + off);
        uil[kv] = *(const short8*)(WihLo + off);
    }
    #pragma unroll
    for (int kv = 0; kv < 8; kv++) asm volatile("" : "+v"(wfh[kv]), "+v"(wfl[kv]));
    #pragma unroll
    for (int kv = 0; kv < KV; kv++) asm volatile("" : "+v"(uih[kv]), "+v"(uil[kv]));

    const int q_u  = l >> 4;           // unit_local quarter (0..3)
    const int bi_m = l & 15;           // batch (MFMA col / cell)
    const int unit = s * 16 + w * 4 + q_u;
    float bias_g[4];
    #pragma unroll
    for (int g = 0; g < 4; g++) bias_g[g] = bsum[d * 1024 + g * 256 + unit];

    float creg = 0.f, mx = -1e30f;
    const int swz = bi_m & 7;
    const int klane = l >> 4;
    const int len_m = lens_sh[bi_m];

    for (int t = 0; t < maxlen; ++t) {
        // ---- (1) issue x-tile loads into REGISTERS (latency overlaps the h-poll) ----
        short8 xreg[NST];
        #pragma unroll
        for (int p = 0; p < NST; p++) {
            const int idx = p * 256 + tid;
            const int bi = idx / CR;
            const int ch = idx - bi * CR;
            const int len_b = lens_sh[bi];
            const int pos = (d == 0) ? t : ((t < len_b) ? (len_b - 1 - t) : t);
            xreg[p] = *(const short8*)(Xin + ((size_t)(c * 16 + bi) * TT + pos) * KIN + ch * 8);
            asm volatile("" : "+v"(xreg[p]));   // pin: poll's "memory" clobber must not force a reload
        }

        // ---- (2) acquire h(t): self-validating retry load (ONE coherent hop) ----
        if (t == 0) {
            const short8 z = {0,0,0,0,0,0,0,0};
            for (int i = tid; i < 512; i += 256) {
                ((short8*)hs_hi)[i] = z;
                ((short8*)hs_lo)[i] = z;
            }
        } else {
            const u32* gbase = hx + (((size_t)(t & 1) * 2 + d) * 64 + c * 16) * 256;
            const u32* p0 = gbase + tid * 4;
            const u32* p1 = p0 + 1024;
            const u32* p2 = p0 + 2048;
            const u32* p3 = p0 + 3072;
            const int expect = (t >> 1) & 1;
            int4v w0, w1, w2, w3;
            int rounds = 0;
            for (;;) {
                asm volatile(
                    "global_load_dwordx4 %0, %4, off sc0 sc1\n\t"
                    "global_load_dwordx4 %1, %5, off sc0 sc1\n\t"
                    "global_load_dwordx4 %2, %6, off sc0 sc1\n\t"
                    "global_load_dwordx4 %3, %7, off sc0 sc1"
                    : "=&v"(w0), "=&v"(w1), "=&v"(w2), "=&v"(w3)
                    : "v"(p0), "v"(p1), "v"(p2), "v"(p3)
                    : "memory");
                asm volatile("s_waitcnt vmcnt(0)"
                    : "+v"(w0), "+v"(w1), "+v"(w2), "+v"(w3) :: "memory");
                u32 aw = 0xFFFFFFFFu, ow = 0u;
                #pragma unroll
                for (int j = 0; j < 4; j++) {
                    aw &= (u32)w0[j]; ow |= (u32)w0[j];
                    aw &= (u32)w1[j]; ow |= (u32)w1[j];
                    aw &= (u32)w2[j]; ow |= (u32)w2[j];
                    aw &= (u32)w3[j]; ow |= (u32)w3[j];
                }
                const int ok = expect ? (int)((aw >> 16) & 1u)
                                      : (int)(((ow >> 16) & 1u) ^ 1u);
                if (__all(ok)) break;
                if (++rounds > (1 << 17)) break;   // valve: degrade, never hang
                __builtin_amdgcn_s_sleep(1);
            }
            // unpack -> swizzled LDS
            const int u0 = (tid & 63) * 4;          // 4 consecutive units
            const int ch = u0 >> 3;                  // chunk of 8 units
            const int co = u0 & 7;                   // 0 or 4 within chunk
            int4v wq[4] = {w0, w1, w2, w3};
            #pragma unroll
            for (int qq = 0; qq < 4; qq++) {
                const int bi = qq * 4 + (tid >> 6);
                u16x4 hi4, lo4;
                #pragma unroll
                for (int j = 0; j < 4; j++) {
                    const u32 wd = (u32)wq[qq][j];
                    hi4[j] = (u16)(wd & 0xFFFFu);
                    lo4[j] = (u16)(wd >> 16);
                }
                *(u16x4*)(hs_hi + bi * 256 + (ch ^ (bi & 7)) * 8 + co) = hi4;
                *(u16x4*)(hs_lo + bi * 256 + (ch ^ (bi & 7)) * 8 + co) = lo4;
            }
        }
        // ---- (3) write staged x regs -> LDS (loads completed during poll) ----
        #pragma unroll
        for (int p = 0; p < NST; p++) {
            const int idx = p * 256 + tid;
            const int bi = idx / CR;
            const int ch = idx - bi * CR;
            *(short8*)(xs + bi * KIN + (ch ^ (bi & 7)) * 8) = xreg[p];
        }
        __syncthreads();   // SYNC-B: xs & hs ready

        // ---- (4) gates = Whh.h (3-term) + Wih.x (2-term); 3 independent acc chains ----
        f32x4 acc_a = {0.f,0.f,0.f,0.f}, acc_b = {0.f,0.f,0.f,0.f}, acc_c = {0.f,0.f,0.f,0.f};
        #pragma unroll
        for (int kv = 0; kv < 8; kv++) {
            const int kc = kv * 4 + klane;
            const short8 bh = *(const short8*)(hs_hi + bi_m * 256 + (kc ^ swz) * 8);
            const short8 bl = *(const short8*)(hs_lo + bi_m * 256 + (kc ^ swz) * 8);
            acc_a = __builtin_amdgcn_mfma_f32_16x16x32_bf16(wfh[kv], bh, acc_a, 0, 0, 0);
            acc_b = __builtin_amdgcn_mfma_f32_16x16x32_bf16(wfl[kv], bh, acc_b, 0, 0, 0);
            acc_c = __builtin_amdgcn_mfma_f32_16x16x32_bf16(wfh[kv], bl, acc_c, 0, 0, 0);
        }
        #pragma unroll
        for (int kv = 0; kv < KV; kv++) {
            const int kc = kv * 4 + klane;
            const short8 bx = *(const short8*)(xs + bi_m * KIN + (kc ^ swz) * 8);
            acc_a = __builtin_amdgcn_mfma_f32_16x16x32_bf16(uih[kv], bx, acc_a, 0, 0, 0);
            acc_b = __builtin_amdgcn_mfma_f32_16x16x32_bf16(uil[kv], bx, acc_b, 0, 0, 0);
        }

        // ---- (5) cell update FULLY IN REGISTERS: this thread holds gates i,f,g,o of (unit, bi_m) ----
        {
            const float gi = acc_a[0] + acc_b[0] + acc_c[0] + bias_g[0];
            const float gf = acc_a[1] + acc_b[1] + acc_c[1] + bias_g[1];
            const float gg = acc_a[2] + acc_b[2] + acc_c[2] + bias_g[2];
            const float go = acc_a[3] + acc_b[3] + acc_c[3] + bias_g[3];
            const float cc = fsigmoid(gf) * creg + fsigmoid(gi) * ftanh(gg);
            creg = cc;
            const float h = fsigmoid(go) * ftanh(cc);
            if (POOL && t < len_m) mx = fmaxf(mx, h);
            const u16 hh = bf16_hi(h);
            const u32 hl = ((u32)bf16_hi(h - bf16f(hh)) & 0xFFFEu) | (u32)(((t + 1) >> 1) & 1);
            ho_pack[bi_m * 17 + w * 4 + q_u] = (u32)hh | (hl << 16);
        }
        __syncthreads();   // SYNC-D: ho_pack ready

        // ---- (6) publish: wave0 -> hx (16B coherent stores, NO wait); wave1 -> H0 ----
        if (w == 0) {
            const int bi = l >> 2, qq = l & 3;
            const int4v pv = *(const int4v*)(ho_pack + bi * 17 + qq * 4);
            u32* dst = hx + (((size_t)((t + 1) & 1) * 2 + d) * 64 + c * 16 + bi) * 256 + s * 16 + qq * 4;
            asm volatile("global_store_dwordx4 %0, %1, off sc0 sc1" :: "v"(dst), "v"(pv) : "memory");
        } else if (WRITE_H && w == 1) {
            const int bi = l >> 2, qq = l & 3;
            const int4v pv = *(const int4v*)(ho_pack + bi * 17 + qq * 4);
            u16x4 hv;
            #pragma unroll
            for (int j = 0; j < 4; j++) hv[j] = (u16)((u32)pv[j] & 0xFFFFu);
            const int len_b = lens_sh[bi];
            const int pos = (d == 0) ? t : ((t < len_b) ? (len_b - 1 - t) : t);
            *(u16x4*)(H0 + ((size_t)(c * 16 + bi) * TT + pos) * 512 + d * 256 + s * 16 + qq * 4) = hv;
        }
        // no trailing barrier: next iteration's SYNC-B orders LDS reuse
    }

    if (POOL) {
        outp[(size_t)(c * 16 + bi_m) * 512 + d * 256 + unit] = mx;
    }
}

// ---------------- host launch ----------------
extern "C" void kernel_launch(void* const* d_in, const int* in_sizes, int n_in,
                              void* d_out, int out_size, void* d_ws, size_t ws_size,
                              hipStream_t stream)
{
    (void)in_sizes; (void)n_in; (void)out_size; (void)ws_size;
    const int*   x     = (const int*)d_in[0];
    const int*   slen  = (const int*)d_in[1];
    const float* embed = (const float*)d_in[2];
    const float* W[16];
    for (int i = 0; i < 16; i++) W[i] = (const float*)d_in[3 + i];
    float* out = (float*)d_out;

    char* p = (char*)d_ws;                                   // total ~63.5 MB
    u16* A0      = (u16*)p;   p += (size_t)MROWS * DIM * 2;  // 16.8 MB
    u16* H0      = (u16*)p;   p += (size_t)MROWS * 512 * 2;  // 33.6 MB
    u16* WihQ0hi = (u16*)p;   p += 524288 * 2;
    u16* WihQ0lo = (u16*)p;   p += 524288 * 2;
    u16* WhhQ0hi = (u16*)p;   p += 524288 * 2;
    u16* WhhQ0lo = (u16*)p;   p += 524288 * 2;
    u16* WihQ1hi = (u16*)p;   p += 1048576 * 2;
    u16* WihQ1lo = (u16*)p;   p += 1048576 * 2;
    u16* WhhQ1hi = (u16*)p;   p += 524288 * 2;
    u16* WhhQ1lo = (u16*)p;   p += 524288 * 2;
    float* bsum  = (float*)p; p += 4096 * 4;
    u32* hxp     = (u32*)p;   p += 131072 * 4;               // 2 layer-regions, parity-tagged

    k_prep<<<10768, 256, 0, stream>>>(
        W[0], W[1], W[2], W[3], W[4], W[5], W[6], W[7],
        W[8], W[9], W[10], W[11], W[12], W[13], W[14], W[15],
        WihQ0hi, WihQ0lo, WhhQ0hi, WhhQ0lo, WihQ1hi, WihQ1lo, WhhQ1hi, WhhQ1lo,
        bsum, hxp);

    k_gather<<<8192, 256, 0, stream>>>(x, embed, A0);

    k_lstm<256, true, false><<<128, 256, 0, stream>>>(
        A0, WhhQ0hi, WhhQ0lo, WihQ0hi, WihQ0lo, bsum, slen,
        H0, nullptr, hxp);

    k_lstm<512, false, true><<<128, 256, 0, stream>>>(
        H0, WhhQ1hi, WhhQ1lo, WihQ1hi, WihQ1lo, bsum + 2048, slen,
        nullptr, out, hxp + 65536);
}